// Round 1
// baseline (4633.080 us; speedup 1.0000x reference)
//
#include <hip/hip_runtime.h>
#include <hip/hip_bf16.h>
#include <stdint.h>

// Problem constants
#define B_    8
#define CIN   64
#define COUT  64
#define HW_   256
#define KS    31
#define PADDED 288   // padded spatial dim for P (pad offset 15, +2 slack)
#define CG    8      // channels per group
#define NG    8      // number of channel groups (CIN/CG)
#define TILE  16     // output spatial tile (both dims)
#define PATCH 48     // staged patch rows/cols (16+31-1=46 real, padded to 48)
#define VP    16     // v-pair count: v = vp*2+dv, dv in {0,1}; v==31 zero-padded

typedef __attribute__((ext_vector_type(8))) short short8;
typedef __attribute__((ext_vector_type(16))) float f32x16;

__device__ __forceinline__ short f2bf(float f) {
    __hip_bfloat16 h = __float2bfloat16(f);
    return __builtin_bit_cast(short, h);
}

// P layout: [b][g][y'][x'][cc] bf16, y',x' in [0,288), value = signal[b][g*8+cc][y'-15][x'-15] or 0
__global__ void pad_input_kernel(const float* __restrict__ sig, short* __restrict__ P) {
    int idx = blockIdx.x * 256 + threadIdx.x;   // total 8*8*288*288 = 5,308,416
    int x = idx % PADDED;
    int t = idx / PADDED;
    int y = t % PADDED;
    t /= PADDED;
    int g = t % NG;
    int b = t / NG;
    int ys = y - 15, xs = x - 15;
    bool in = (ys >= 0 && ys < HW_ && xs >= 0 && xs < HW_);
    const float* sp = sig + (((size_t)(b*CIN + g*CG) * HW_ + ys) * HW_ + xs);
    short8 v;
#pragma unroll
    for (int cc = 0; cc < CG; ++cc) {
        float f = in ? sp[(size_t)cc * HW_ * HW_] : 0.0f;
        v[cc] = f2bf(f);
    }
    *reinterpret_cast<short8*>(P + (size_t)idx * CG) = v;
}

// Wp layout (32x32x16 MFMA): [g][u][vp][mt(2)][o'(32)][k(16)]
// k = dv*8 + cc, v = vp*2 + dv (v==31 zero-padded), o = mt*32 + o'
// A-frag lane mapping: row(o') = lane&31, k-base = (lane>>5)*8, 8 contiguous shorts (16 B)
__global__ void pack_weight_kernel(const float* __restrict__ w, short* __restrict__ Wp) {
    int idx = blockIdx.x * 256 + threadIdx.x;   // total 8*31*16*1024 = 4,063,232
    int k = idx & 15;
    int t = idx >> 4;
    int op = t & 31; t >>= 5;
    int mt = t & 1;  t >>= 1;
    int vp = t & 15; t >>= 4;
    int u = t % KS;
    int g = t / KS;
    int dv = k >> 3, cc = k & 7;
    int v = vp * 2 + dv;
    int o = mt * 32 + op;
    float f = (v < KS) ? w[(((size_t)o * CIN + g * CG + cc) * KS + u) * KS + v] : 0.0f;
    Wp[idx] = f2bf(f);
}

// Main conv, R3: 32x32x16 MFMA.
// One block = 64 out-ch x 16x16 spatial tile for one batch image. 4 waves.
// Wave w owns rows 4w..4w+3 = two 32x32 n-tiles (n = rowsub*16 + x, rowsub=(lane>>4)&1).
// Per wave: acc[2 m-tiles][2 n-tiles] of f32x16 = 64 VGPR; register ping-pong of
// A-frags (global Wp) and B-frags (LDS patch) at K=16 step granularity.
// launch_bounds(256,3): target 3 blocks/CU (12 waves) for latency hiding; frag+acc = 96 VGPR.
__global__ __launch_bounds__(256, 3)
void conv_mfma_kernel(const short* __restrict__ P, const short* __restrict__ Wp,
                      const float* __restrict__ bias, float* __restrict__ out) {
    __shared__ __align__(16) short patch[PATCH * PATCH * CG];  // 36,864 B (3 blocks/CU fit)

    int bid = blockIdx.x;             // [0,2048)
    int b  = bid >> 8;
    int ty = (bid >> 4) & 15;
    int tx = bid & 15;
    int y0 = ty * TILE, x0 = tx * TILE;

    int tid  = threadIdx.x;
    int w    = tid >> 6;
    int lane = tid & 63;
    int x15  = lane & 15;
    int rs   = (lane >> 4) & 1;       // row-sub within n-tile (n>>4)
    int dv   = lane >> 5;             // k-half: v offset 0/1

    // A-frag lane offset within a 1024-elem (g,u,vp) block: o'=lane&31, k-base=dv*8
    const int a_off = (lane & 31) * 16 + dv * 8;

    // B-frag LDS element offsets (t = n-tile 0/1): row = 4w + 2t + rs, col = x15 + dv
    int boff[2];
#pragma unroll
    for (int t = 0; t < 2; ++t)
        boff[t] = ((w * 4 + t * 2 + rs) * PATCH + x15 + dv) * CG;

    f32x16 acc[2][2];
#pragma unroll
    for (int m = 0; m < 2; ++m)
#pragma unroll
        for (int t = 0; t < 2; ++t)
            acc[m][t] = (f32x16)(0.0f);

    for (int g = 0; g < NG; ++g) {
        __syncthreads();   // protect previous iteration's LDS reads
        // ---- stage 48x48x8 bf16 patch via async global->LDS (16B per lane) ----
        const short* Pbase = P + (size_t)(b * NG + g) * PADDED * PADDED * CG;
#pragma unroll
        for (int it = 0; it < 9; ++it) {
            int t = it * 256 + tid;        // [0, 2304)
            int r  = t / PATCH;
            int cl = t - r * PATCH;
            const short* gsrc = Pbase + ((size_t)(y0 + r) * PADDED + (x0 + cl)) * CG;
            __builtin_amdgcn_global_load_lds(
                (const __attribute__((address_space(1))) void*)gsrc,
                (__attribute__((address_space(3))) void*)(patch + (size_t)t * CG),
                16, 0, 0);
        }
        __syncthreads();   // drains vmcnt(0): staging complete

        const short* Wg = Wp + (size_t)g * KS * VP * 1024;

        // ---- software-pipelined K loop: 31 u-taps x 16 v-pairs, K=16 per step ----
        short8 a[2][2], bf[2][2];
        // prologue: load (u=0, vp=0) into buffer 0
#pragma unroll
        for (int m = 0; m < 2; ++m)
            a[0][m] = *reinterpret_cast<const short8*>(Wg + m * 512 + a_off);
#pragma unroll
        for (int t = 0; t < 2; ++t)
            bf[0][t] = *reinterpret_cast<const short8*>(patch + boff[t]);

        for (int u = 0; u < KS; ++u) {
#pragma unroll
            for (int vp = 0; vp < VP; ++vp) {
                int p = vp & 1;
                int nu  = (vp == VP - 1) ? u + 1 : u;
                int nvp = (vp + 1) & (VP - 1);
                if (nu < KS) {
                    const short* Wn = Wg + (size_t)(nu * VP + nvp) * 1024;
#pragma unroll
                    for (int m = 0; m < 2; ++m)
                        a[p ^ 1][m] = *reinterpret_cast<const short8*>(Wn + m * 512 + a_off);
                    int bo = (nu * PATCH + nvp * 2) * CG;
#pragma unroll
                    for (int t = 0; t < 2; ++t)
                        bf[p ^ 1][t] = *reinterpret_cast<const short8*>(patch + boff[t] + bo);
                }
#pragma unroll
                for (int m = 0; m < 2; ++m)
#pragma unroll
                    for (int t = 0; t < 2; ++t)
                        acc[m][t] = __builtin_amdgcn_mfma_f32_32x32x16_bf16(
                            a[p][m], bf[p][t], acc[m][t], 0, 0, 0);
            }
        }
    }

    // ---- epilogue: C/D 32x32 layout: col=lane&31 (n = rs*16+x15),
    //      row = (r&3) + 8*(r>>2) + 4*dv  (o within the 32-o m-tile)
#pragma unroll
    for (int m = 0; m < 2; ++m) {
#pragma unroll
        for (int t = 0; t < 2; ++t) {
            int y = y0 + w * 4 + t * 2 + rs;
#pragma unroll
            for (int r = 0; r < 16; ++r) {
                int o = m * 32 + (r & 3) + 8 * (r >> 2) + 4 * dv;
                out[(((size_t)b * COUT + o) * HW_ + y) * HW_ + x0 + x15] =
                    acc[m][t][r] + bias[o];
            }
        }
    }
}

extern "C" void kernel_launch(void* const* d_in, const int* in_sizes, int n_in,
                              void* d_out, int out_size, void* d_ws, size_t ws_size,
                              hipStream_t stream) {
    const float* sig  = (const float*)d_in[0];
    const float* wgt  = (const float*)d_in[1];
    const float* bias = (const float*)d_in[2];
    float* out = (float*)d_out;

    // ws layout: Wp (4,063,232 shorts = 8,126,464 B) then P (42,467,328 shorts = 84,934,656 B)
    short* Wp = (short*)d_ws;
    short* P  = (short*)d_ws + 4063232;

    pack_weight_kernel<<<15872, 256, 0, stream>>>(wgt, Wp);
    pad_input_kernel<<<20736, 256, 0, stream>>>(sig, P);
    conv_mfma_kernel<<<2048, 256, 0, stream>>>(P, Wp, bias, out);
}

// Round 2
// 3998.084 us; speedup vs baseline: 1.1588x; 1.1588x over previous
//
#include <hip/hip_runtime.h>
#include <hip/hip_bf16.h>
#include <stdint.h>

// Problem constants
#define B_    8
#define CIN   64
#define COUT  64
#define HW_   256
#define KS    31
#define PADDED 288   // padded spatial dim for P (pad offset 15, +2 slack)
#define CG    8      // channels per group
#define NG    8      // number of channel groups (CIN/CG)
#define TILE  16     // output spatial tile (both dims)
#define PATCH 48     // staged patch rows/cols (16+31-1=46 real, padded to 48)
#define VP    16     // v-pair count: v = vp*2+dv, dv in {0,1}; v==31 zero-padded
#define NSTEP (KS * VP)  // 496 K-steps of K=16 per channel-group

typedef __attribute__((ext_vector_type(8))) short short8;
typedef __attribute__((ext_vector_type(16))) float f32x16;

__device__ __forceinline__ short f2bf(float f) {
    __hip_bfloat16 h = __float2bfloat16(f);
    return __builtin_bit_cast(short, h);
}

// P layout: [b][g][y'][x'][cc] bf16, y',x' in [0,288), value = signal[b][g*8+cc][y'-15][x'-15] or 0
__global__ void pad_input_kernel(const float* __restrict__ sig, short* __restrict__ P) {
    int idx = blockIdx.x * 256 + threadIdx.x;   // total 8*8*288*288 = 5,308,416
    int x = idx % PADDED;
    int t = idx / PADDED;
    int y = t % PADDED;
    t /= PADDED;
    int g = t % NG;
    int b = t / NG;
    int ys = y - 15, xs = x - 15;
    bool in = (ys >= 0 && ys < HW_ && xs >= 0 && xs < HW_);
    const float* sp = sig + (((size_t)(b*CIN + g*CG) * HW_ + ys) * HW_ + xs);
    short8 v;
#pragma unroll
    for (int cc = 0; cc < CG; ++cc) {
        float f = in ? sp[(size_t)cc * HW_ * HW_] : 0.0f;
        v[cc] = f2bf(f);
    }
    *reinterpret_cast<short8*>(P + (size_t)idx * CG) = v;
}

// Wp layout (32x32x16 MFMA): [g][u][vp][mt(2)][o'(32)][k(16)]
// k = dv*8 + cc, v = vp*2 + dv (v==31 zero-padded), o = mt*32 + o'
// A-frag lane mapping: row(o') = lane&31, k-base = (lane>>5)*8, 8 contiguous shorts (16 B)
// NOTE: contiguous in step order s = u*16+vp -> A prefetch address is Wg + s*1024.
__global__ void pack_weight_kernel(const float* __restrict__ w, short* __restrict__ Wp) {
    int idx = blockIdx.x * 256 + threadIdx.x;   // total 8*31*16*1024 = 4,063,232
    int k = idx & 15;
    int t = idx >> 4;
    int op = t & 31; t >>= 5;
    int mt = t & 1;  t >>= 1;
    int vp = t & 15; t >>= 4;
    int u = t % KS;
    int g = t / KS;
    int dv = k >> 3, cc = k & 7;
    int v = vp * 2 + dv;
    int o = mt * 32 + op;
    float f = (v < KS) ? w[(((size_t)o * CIN + g * CG + cc) * KS + u) * KS + v] : 0.0f;
    Wp[idx] = f2bf(f);
}

// Main conv, R4: 32x32x16 MFMA + depth-4 A-prefetch / depth-2 B-prefetch.
// One block = 64 out-ch x 16x16 spatial tile for one batch image. 4 waves.
// Wave w owns rows 4w..4w+3 = two 32-wide n-tiles (n = rs*16 + x15, row = 4w + 2t + rs).
// R1 diagnosis: latency-bound on the A (weight) stream (Wp 8.1MB > 4MiB L2 -> L3-hit
// ~400-600cyc; 1-step lookahead = ~128cyc hide -> MfmaUtil 41.6%). Fix: circular
// register pipeline, A depth 4 (addresses are linear in step index), B depth 2.
// VGPR: 64 acc (AGPR) + ~80 arch -> 3 waves/SIMD; hide capacity 3*4*32 ~= 384 cyc.
__global__ __launch_bounds__(256, 3)
void conv_mfma_kernel(const short* __restrict__ P, const short* __restrict__ Wp,
                      const float* __restrict__ bias, float* __restrict__ out) {
    __shared__ __align__(16) short patch[PATCH * PATCH * CG];  // 36,864 B

    int bid = blockIdx.x;             // [0,2048)
    int b  = bid >> 8;
    int ty = (bid >> 4) & 15;
    int tx = bid & 15;
    int y0 = ty * TILE, x0 = tx * TILE;

    int tid  = threadIdx.x;
    int w    = tid >> 6;
    int lane = tid & 63;
    int x15  = lane & 15;
    int rs   = (lane >> 4) & 1;       // row-sub within n-tile (n>>4)
    int dv   = lane >> 5;             // k-half: v offset 0/1

    // A-frag lane offset within a 1024-elem (g,u,vp) block: o'=lane&31, k-base=dv*8
    const int a_off = (lane & 31) * 16 + dv * 8;

    // B-frag LDS element offsets (t = n-tile 0/1): row = 4w + 2t + rs, col = x15 + dv
    int boff[2];
#pragma unroll
    for (int t = 0; t < 2; ++t)
        boff[t] = ((w * 4 + t * 2 + rs) * PATCH + x15 + dv) * CG;

    f32x16 acc[2][2];
#pragma unroll
    for (int m = 0; m < 2; ++m)
#pragma unroll
        for (int t = 0; t < 2; ++t)
            acc[m][t] = (f32x16)(0.0f);

    for (int g = 0; g < NG; ++g) {
        __syncthreads();   // drain prev iter's LDS reads (incl. in-flight B prefetch)
        // ---- stage 48x48x8 bf16 patch via async global->LDS (16B per lane) ----
        const short* Pbase = P + (size_t)(b * NG + g) * PADDED * PADDED * CG;
#pragma unroll
        for (int it = 0; it < 9; ++it) {
            int t = it * 256 + tid;        // [0, 2304)
            int r  = t / PATCH;
            int cl = t - r * PATCH;
            const short* gsrc = Pbase + ((size_t)(y0 + r) * PADDED + (x0 + cl)) * CG;
            __builtin_amdgcn_global_load_lds(
                (const __attribute__((address_space(1))) void*)gsrc,
                (__attribute__((address_space(3))) void*)(patch + (size_t)t * CG),
                16, 0, 0);
        }
        __syncthreads();   // drains vmcnt(0): staging complete

        const short* Wg = Wp + (size_t)g * NSTEP * 1024;
        const short* Wa = Wg + a_off;      // per-lane A base; step s block at +s*1024

        // ---- K loop: 496 steps (31 u-taps x 16 v-pairs), K=16 per step ----
        // circular prefetch: a[s%4] holds A of step s; bf[s%2] holds B of step s.
        short8 a[4][2], bf[2][2];
#pragma unroll
        for (int d = 0; d < 4; ++d) {
            a[d][0] = *reinterpret_cast<const short8*>(Wa + (size_t)d * 1024);
            a[d][1] = *reinterpret_cast<const short8*>(Wa + (size_t)d * 1024 + 512);
        }
#pragma unroll
        for (int d = 0; d < 2; ++d) {
            // step d: u=0, vp=d -> offset vp*2*CG = d*16 elements
            bf[d][0] = *reinterpret_cast<const short8*>(patch + boff[0] + d * 16);
            bf[d][1] = *reinterpret_cast<const short8*>(patch + boff[1] + d * 16);
        }

        for (int kk = 0; kk < NSTEP; kk += 4) {
#pragma unroll
            for (int d = 0; d < 4; ++d) {
                int s = kk + d;
                // consume a[d] (=a[s%4]) and bf[d&1] (=bf[s%2])
#pragma unroll
                for (int m = 0; m < 2; ++m)
#pragma unroll
                    for (int t = 0; t < 2; ++t)
                        acc[m][t] = __builtin_amdgcn_mfma_f32_32x32x16_bf16(
                            a[d][m], bf[d & 1][t], acc[m][t], 0, 0, 0);
                // prefetch A for step s+4 into a[d]. Unconditional: at s+4>495 this
                // reads past Wg into following workspace (allocated; data unused).
                {
                    const short* Wn = Wa + (size_t)(s + 4) * 1024;
                    a[d][0] = *reinterpret_cast<const short8*>(Wn);
                    a[d][1] = *reinterpret_cast<const short8*>(Wn + 512);
                }
                // prefetch B for step s+2 into bf[d&1]. At s+2>495 reads the PATCH=48
                // slack rows/cols (max elem 17,816 < 18,432) -- in-bounds, unused.
                {
                    int sp = s + 2;
                    int off = (sp >> 4) * (PATCH * CG) + (sp & 15) * (2 * CG);
                    bf[d & 1][0] = *reinterpret_cast<const short8*>(patch + boff[0] + off);
                    bf[d & 1][1] = *reinterpret_cast<const short8*>(patch + boff[1] + off);
                }
            }
        }
    }

    // ---- epilogue: C/D 32x32 layout: col=lane&31 (n = rs*16+x15),
    //      row = (r&3) + 8*(r>>2) + 4*dv  (o within the 32-o m-tile)
#pragma unroll
    for (int m = 0; m < 2; ++m) {
#pragma unroll
        for (int t = 0; t < 2; ++t) {
            int y = y0 + w * 4 + t * 2 + rs;
#pragma unroll
            for (int r = 0; r < 16; ++r) {
                int o = m * 32 + (r & 3) + 8 * (r >> 2) + 4 * dv;
                out[(((size_t)b * COUT + o) * HW_ + y) * HW_ + x0 + x15] =
                    acc[m][t][r] + bias[o];
            }
        }
    }
}

extern "C" void kernel_launch(void* const* d_in, const int* in_sizes, int n_in,
                              void* d_out, int out_size, void* d_ws, size_t ws_size,
                              hipStream_t stream) {
    const float* sig  = (const float*)d_in[0];
    const float* wgt  = (const float*)d_in[1];
    const float* bias = (const float*)d_in[2];
    float* out = (float*)d_out;

    // ws layout: Wp (4,063,232 shorts = 8,126,464 B) then P (42,467,328 shorts = 84,934,656 B)
    short* Wp = (short*)d_ws;
    short* P  = (short*)d_ws + 4063232;

    pack_weight_kernel<<<15872, 256, 0, stream>>>(wgt, Wp);
    pad_input_kernel<<<20736, 256, 0, stream>>>(sig, P);
    conv_mfma_kernel<<<2048, 256, 0, stream>>>(P, Wp, bias, out);
}